// Round 4
// baseline (993.655 us; speedup 1.0000x reference)
//
#include <hip/hip_runtime.h>
#include <hip/hip_bf16.h>
#include <stdint.h>

// B=8, N=1024, D=1024.  out = relu(adj @ (y@W) / adj_sumrow + b + x)
// R4: B-operand direct global->register MFMA fragments (no LDS), A-operand
// manually staged (f32->bf16 cvt fused) with register double-buffering,
// lgkm-only barriers so global prefetches stay in flight. Prep = W^T only.

typedef float  f32x4  __attribute__((ext_vector_type(4)));
typedef __bf16 bf16x8 __attribute__((ext_vector_type(8)));
typedef unsigned short u16x8 __attribute__((ext_vector_type(8)));

__device__ __forceinline__ unsigned short f2bf(float f) {
  union { float f; unsigned int u; } c; c.f = f;
  unsigned int u = c.u;
  u += 0x7FFFu + ((u >> 16) & 1u);   // RNE; inputs finite
  return (unsigned short)(u >> 16);
}

__device__ __forceinline__ bf16x8 cvt8(float4 a, float4 b) {
  u16x8 u;
  u[0] = f2bf(a.x); u[1] = f2bf(a.y); u[2] = f2bf(a.z); u[3] = f2bf(a.w);
  u[4] = f2bf(b.x); u[5] = f2bf(b.y); u[6] = f2bf(b.z); u[7] = f2bf(b.w);
  union { u16x8 u; bf16x8 h; } c; c.u = u; return c.h;
}

// barrier that does NOT drain vmcnt: LDS ops ordered, global loads stay in flight
__device__ __forceinline__ void bar_lds() {
  asm volatile("s_waitcnt lgkmcnt(0)\n\ts_barrier" ::: "memory");
}

__device__ __forceinline__ void zero_acc(f32x4 acc[4][4]) {
#pragma unroll
  for (int i = 0; i < 4; ++i)
#pragma unroll
    for (int j = 0; j < 4; ++j)
#pragma unroll
      for (int r = 0; r < 4; ++r) acc[i][j][r] = 0.0f;
}

// ---------------- prep: Wt[n][k] = W[k][n], f32 -> bf16 ----------------

__global__ __launch_bounds__(256) void k_prepW(
    const float* __restrict__ W, unsigned short* __restrict__ Wt)
{
  __shared__ float t[64][65];
  const int tx = threadIdx.x, ty = threadIdx.y;
  const int n0 = blockIdx.x * 64, k0 = blockIdx.y * 64;
#pragma unroll
  for (int r = ty; r < 64; r += 4)
    t[r][tx] = W[(size_t)(k0 + r) * 1024 + n0 + tx];
  __syncthreads();
#pragma unroll
  for (int r = ty; r < 64; r += 4)
    Wt[(size_t)(n0 + r) * 1024 + k0 + tx] = f2bf(t[tx][r]);
}

// ---------------- GEMM1: Sup2 = Wt @ Y^T  (Sup2[d][8192] bf16) ----------------
// A = Wt [1024][1024] bf16 (staged via LDS, swizzled), B = Y [8192][1024] f32
// (direct global->reg fragments + cvt). 128x128 tile, BK=64, 4 waves 2x2.

__global__ __launch_bounds__(256) void k_gemm1(
    const unsigned short* __restrict__ Wt,
    const float* __restrict__ Y,
    unsigned short* __restrict__ Sup2)
{
  __shared__ __align__(16) unsigned short lA[128 * 64];
  const int tid = threadIdx.x;
  const int m0 = blockIdx.x * 128;   // d-dim (8 tiles) — fast dim: shares Y n-stripe in L2
  const int n0 = blockIdx.y * 128;   // y-row dim (64 tiles)
  const int lane = tid & 63, wave = tid >> 6;
  const int wm = (wave >> 1) * 64, wn = (wave & 1) * 64;
  const int quad = lane >> 4, l16 = lane & 15;
  const int sr = tid >> 3;           // staging row 0..31 (+w*32)
  const int sc = tid & 7;            // staging chunk 0..7

  f32x4 acc[4][4];
  zero_acc(acc);

  bf16x8 sva[2][4];
#pragma unroll
  for (int w = 0; w < 4; ++w)
    sva[0][w] = *(const bf16x8*)(void*)(Wt + (size_t)(m0 + w * 32 + sr) * 1024 + sc * 8);

  int cur = 0;
#pragma unroll 1
  for (int k0 = 0; k0 < 1024; k0 += 64) {
    bar_lds();                                   // prior LDS reads done
    if (k0 + 64 < 1024) {
#pragma unroll
      for (int w = 0; w < 4; ++w)
        sva[cur ^ 1][w] = *(const bf16x8*)(void*)(Wt + (size_t)(m0 + w * 32 + sr) * 1024 + k0 + 64 + sc * 8);
    }
#pragma unroll
    for (int w = 0; w < 4; ++w) {
      const int row = w * 32 + sr;
      *(bf16x8*)(void*)(lA + row * 64 + ((sc + row) & 7) * 8) = sva[cur][w];
    }
    bar_lds();                                   // LDS writes visible; globals in flight

#pragma unroll
    for (int h = 0; h < 2; ++h) {
      bf16x8 bfr[4], af[4];
#pragma unroll
      for (int j = 0; j < 4; ++j) {
        const float4* p = (const float4*)(Y + (size_t)(n0 + wn + j * 16 + l16) * 1024 + k0 + (h * 4 + quad) * 8);
        bfr[j] = cvt8(p[0], p[1]);
      }
#pragma unroll
      for (int i = 0; i < 4; ++i) {
        const int r = wm + i * 16 + l16;
        af[i] = *(const bf16x8*)(void*)(lA + r * 64 + ((h * 4 + quad + r) & 7) * 8);
      }
#pragma unroll
      for (int i = 0; i < 4; ++i)
#pragma unroll
        for (int j = 0; j < 4; ++j)
          acc[i][j] = __builtin_amdgcn_mfma_f32_16x16x32_bf16(af[i], bfr[j], acc[i][j], 0, 0, 0);
    }
    cur ^= 1;
  }

  // epilogue: row-major Sup2 (rows = d)
#pragma unroll
  for (int i = 0; i < 4; ++i) {
    const int mb = m0 + wm + i * 16 + quad * 4;
#pragma unroll
    for (int r = 0; r < 4; ++r) {
      unsigned short* row = Sup2 + ((size_t)(mb + r) << 13);
#pragma unroll
      for (int j = 0; j < 4; ++j)
        row[n0 + wn + j * 16 + l16] = f2bf(acc[i][j][r]);
    }
  }
}

// ------- GEMM2: out = relu(adj@Sup / rowsum + bias + x), f32 out -------
// A = adj [1024][1024] f32 per batch (manual cvt->LDS, reg-dbuf),
// B = Sup2 rows d, stride 8192, col slice b*1024 (direct bf16 fragments).

__global__ __launch_bounds__(256) void k_gemm2(
    const float* __restrict__ Adj,
    const unsigned short* __restrict__ Sup2,
    const float* __restrict__ x,
    const float* __restrict__ sumrow,
    const float* __restrict__ bias,
    float* __restrict__ out)
{
  __shared__ __align__(16) unsigned short lA[128 * 64];
  const int tid = threadIdx.x;
  const int n0 = blockIdx.x * 128;   // d-dim (8) — fast: shares adj m-stripe in L2
  const int m0 = blockIdx.y * 128;   // node dim (8)
  const int b  = blockIdx.z;
  const float* A = Adj + ((size_t)b << 20);
  const unsigned short* Bt = Sup2 + ((size_t)b << 10);   // row j: + j*8192

  const int lane = tid & 63, wave = tid >> 6;
  const int wm = (wave >> 1) * 64, wn = (wave & 1) * 64;
  const int quad = lane >> 4, l16 = lane & 15;
  const int sr = tid >> 3, sc = tid & 7;

  f32x4 acc[4][4];
  zero_acc(acc);

  float4 sv[2][8];
#pragma unroll
  for (int w = 0; w < 4; ++w) {
    const float4* p = (const float4*)(A + (size_t)(m0 + w * 32 + sr) * 1024 + sc * 8);
    sv[0][2 * w] = p[0]; sv[0][2 * w + 1] = p[1];
  }

  int cur = 0;
#pragma unroll 1
  for (int k0 = 0; k0 < 1024; k0 += 64) {
    bar_lds();
    if (k0 + 64 < 1024) {
#pragma unroll
      for (int w = 0; w < 4; ++w) {
        const float4* p = (const float4*)(A + (size_t)(m0 + w * 32 + sr) * 1024 + k0 + 64 + sc * 8);
        sv[cur ^ 1][2 * w] = p[0]; sv[cur ^ 1][2 * w + 1] = p[1];
      }
    }
#pragma unroll
    for (int w = 0; w < 4; ++w) {
      const int row = w * 32 + sr;
      *(bf16x8*)(void*)(lA + row * 64 + ((sc + row) & 7) * 8) = cvt8(sv[cur][2 * w], sv[cur][2 * w + 1]);
    }
    bar_lds();

#pragma unroll
    for (int h = 0; h < 2; ++h) {
      bf16x8 bfr[4], af[4];
#pragma unroll
      for (int j = 0; j < 4; ++j)
        bfr[j] = *(const bf16x8*)(void*)(Bt + (size_t)(n0 + wn + j * 16 + l16) * 8192 + k0 + (h * 4 + quad) * 8);
#pragma unroll
      for (int i = 0; i < 4; ++i) {
        const int r = wm + i * 16 + l16;
        af[i] = *(const bf16x8*)(void*)(lA + r * 64 + ((h * 4 + quad + r) & 7) * 8);
      }
#pragma unroll
      for (int i = 0; i < 4; ++i)
#pragma unroll
        for (int j = 0; j < 4; ++j)
          acc[i][j] = __builtin_amdgcn_mfma_f32_16x16x32_bf16(af[i], bfr[j], acc[i][j], 0, 0, 0);
    }
    cur ^= 1;
  }

  const float* xb = x   + ((size_t)b << 20);
  float*       ob = out + ((size_t)b << 20);
  const float* srow = sumrow + ((size_t)b << 10);

  float bv[4];
#pragma unroll
  for (int j = 0; j < 4; ++j) bv[j] = bias[n0 + wn + j * 16 + l16];

#pragma unroll
  for (int i = 0; i < 4; ++i) {
    const int mb = m0 + wm + i * 16 + quad * 4;
#pragma unroll
    for (int r = 0; r < 4; ++r) {
      const int m = mb + r;
      const float inv = 1.0f / srow[m];
#pragma unroll
      for (int j = 0; j < 4; ++j) {
        const int n = n0 + wn + j * 16 + l16;
        const size_t idx = (((size_t)m) << 10) + n;
        float v = acc[i][j][r] * inv + bv[j] + xb[idx];
        ob[idx] = fmaxf(v, 0.0f);
      }
    }
  }
}

// ---------------- launcher ----------------

extern "C" void kernel_launch(void* const* d_in, const int* in_sizes, int n_in,
                              void* d_out, int out_size, void* d_ws, size_t ws_size,
                              hipStream_t stream) {
  const float* x      = (const float*)d_in[0];
  const float* y      = (const float*)d_in[1];
  const float* adj    = (const float*)d_in[2];
  const float* sumrow = (const float*)d_in[3];
  const float* W      = (const float*)d_in[4];
  const float* bias   = (const float*)d_in[5];
  float* out = (float*)d_out;

  char* ws = (char*)d_ws;
  unsigned short* wt   = (unsigned short*)(ws);                      //  2 MB
  unsigned short* sup2 = (unsigned short*)(ws + ((size_t)2 << 20));  // 16 MB

  k_prepW<<<dim3(16, 16), dim3(64, 4), 0, stream>>>(W, wt);
  k_gemm1<<<dim3(8, 64), dim3(256), 0, stream>>>(wt, y, sup2);
  k_gemm2<<<dim3(8, 8, 8), dim3(256), 0, stream>>>(adj, sup2, x, sumrow, bias, out);
}

// Round 5
// 204.917 us; speedup vs baseline: 4.8491x; 4.8491x over previous
//
#include <hip/hip_runtime.h>
#include <hip/hip_bf16.h>
#include <stdint.h>

// B=8, N=1024, D=1024.  out = relu(adj @ (y@W) / adj_sumrow + b + x)
// R5: revert to R3 staging (global_load_lds both operands — R4 proved direct
// global fragment loads are scatters). New: BK=32 with 4-deep pipeline
// (prefetch 3 stages ahead > HBM latency), raw s_barrier + exact vmcnt tail.

typedef float  f32x4  __attribute__((ext_vector_type(4)));
typedef __bf16 bf16x8 __attribute__((ext_vector_type(8)));

__device__ __forceinline__ unsigned short f2bf(float f) {
  union { float f; unsigned int u; } c; c.f = f;
  unsigned int u = c.u;
  u += 0x7FFFu + ((u >> 16) & 1u);   // RNE; inputs finite
  return (unsigned short)(u >> 16);
}

__device__ __forceinline__ void async_cp16(const void* g, void* l) {
  __builtin_amdgcn_global_load_lds(
      (const __attribute__((address_space(1))) unsigned int*)g,
      (__attribute__((address_space(3))) unsigned int*)l, 16, 0, 0);
}

__device__ __forceinline__ void bar() { asm volatile("s_barrier" ::: "memory"); }

__device__ __forceinline__ void zero_acc(f32x4 acc[4][4]) {
#pragma unroll
  for (int i = 0; i < 4; ++i)
#pragma unroll
    for (int j = 0; j < 4; ++j)
#pragma unroll
      for (int r = 0; r < 4; ++r) acc[i][j][r] = 0.0f;
}

// ---------------- fused pre-pass ----------------
// blocks [0,16384): y/adj f32->bf16 ; blocks [16384,16640): W transpose+cvt

__global__ __launch_bounds__(256) void k_prep(
    const float4* __restrict__ y4, const float4* __restrict__ a4,
    ushort4* __restrict__ yb, ushort4* __restrict__ ab,
    const float* __restrict__ W, unsigned short* __restrict__ Wt)
{
  __shared__ float t[64][65];
  const int bid = blockIdx.x;
  if (bid < 16384) {
    const int i = bid * 256 + threadIdx.x;
    const bool isY = i < 2097152;
    const float4 v = isY ? y4[i] : a4[i - 2097152];
    ushort4 p;
    p.x = f2bf(v.x); p.y = f2bf(v.y); p.z = f2bf(v.z); p.w = f2bf(v.w);
    if (isY) yb[i] = p; else ab[i - 2097152] = p;
  } else {
    const int id = bid - 16384;
    const int n0 = (id & 15) * 64, k0 = (id >> 4) * 64;
    const int tx = threadIdx.x & 63, ty = threadIdx.x >> 6;
#pragma unroll
    for (int r = ty; r < 64; r += 4)
      t[r][tx] = W[(size_t)(k0 + r) * 1024 + n0 + tx];
    __syncthreads();
#pragma unroll
    for (int r = ty; r < 64; r += 4)
      Wt[(size_t)(n0 + r) * 1024 + k0 + tx] = f2bf(t[tx][r]);
  }
}

// -------- mainloop: 128x128 tile, BK=32, 4-stage pipeline, swizzled LDS --------
// LDS stage = 16 KB: A 128x32 bf16 (rows 64 B) then B 128x32. Chunk swizzle:
// phys16B = (logical + row) & 3 -> 2-way bank aliasing only (free).
// global_load_lds: lane L covers row L>>2, phys chunk L&3, so the global
// column carries the inverse permutation ((L&3)-(L>>2))&3.

__device__ __forceinline__ void gemm_pipe(
    const unsigned short* __restrict__ A,  int sA,
    const unsigned short* __restrict__ Bt, int sB,
    int m0, int n0, f32x4 acc[4][4], unsigned short* lsm, int tid)
{
  const int lane = tid & 63, wave = tid >> 6;
  const int wm = (wave >> 1) * 64, wn = (wave & 1) * 64;
  const int quad = lane >> 4, l16 = lane & 15;
  const int rg   = lane >> 2;                    // row within 16-row granule
  const int colo = (((lane & 3) - rg) & 3) * 8;  // inverse-swizzled k offset

  auto issue_stage = [&](int s) {
    const int k0 = s << 5;
    unsigned short* ls = lsm + (s & 3) * 8192;
#pragma unroll
    for (int t = 0; t < 2; ++t) {
      const int g = wave * 2 + t;                // wave-uniform granule id
      async_cp16(A  + (size_t)(m0 + g * 16 + rg) * sA + k0 + colo, ls + g * 512);
      async_cp16(Bt + (size_t)(n0 + g * 16 + rg) * sB + k0 + colo, ls + 4096 + g * 512);
    }
  };

  issue_stage(0); issue_stage(1); issue_stage(2);

#pragma unroll 1
  for (int s = 0; s < 32; ++s) {
    if (s < 29) {
      issue_stage(s + 3);
      asm volatile("s_waitcnt vmcnt(12)" ::: "memory");   // stage s complete
    } else if (s == 29) { asm volatile("s_waitcnt vmcnt(8)" ::: "memory");
    } else if (s == 30) { asm volatile("s_waitcnt vmcnt(4)" ::: "memory");
    } else              { asm volatile("s_waitcnt vmcnt(0)" ::: "memory"); }
    bar();                                       // all waves staged s

    const unsigned short* ls = lsm + (s & 3) * 8192;
    bf16x8 af[4], bfr[4];
#pragma unroll
    for (int i = 0; i < 4; ++i) {
      const int r = wm + i * 16 + l16;
      af[i]  = *(const bf16x8*)(ls + r * 32 + ((quad + r) & 3) * 8);
    }
#pragma unroll
    for (int j = 0; j < 4; ++j) {
      const int r = wn + j * 16 + l16;
      bfr[j] = *(const bf16x8*)(ls + 4096 + r * 32 + ((quad + r) & 3) * 8);
    }
#pragma unroll
    for (int i = 0; i < 4; ++i)
#pragma unroll
      for (int j = 0; j < 4; ++j)
        acc[i][j] = __builtin_amdgcn_mfma_f32_16x16x32_bf16(af[i], bfr[j], acc[i][j], 0, 0, 0);

    asm volatile("s_waitcnt lgkmcnt(0)" ::: "memory");
    bar();                                       // reads done before re-stage
  }
}

// ---------------- GEMM1: Sup2[d][b*1024+n] = (y@W)^T ----------------

__global__ __launch_bounds__(256) void k_gemm1(
    const unsigned short* __restrict__ Wt,    // [1024][1024]
    const unsigned short* __restrict__ Ybf,   // [8192][1024]
    unsigned short* __restrict__ Sup2)        // [1024][8192]
{
  __shared__ __align__(16) unsigned short lsm[4 * 8192];
  const int tid = threadIdx.x;
  const int n0 = blockIdx.x * 128, m0 = blockIdx.y * 128;

  f32x4 acc[4][4];
  zero_acc(acc);
  gemm_pipe(Wt, 1024, Ybf, 1024, m0, n0, acc, lsm, tid);

  const int lane = tid & 63, wave = tid >> 6;
  const int wm = (wave >> 1) * 64, wn = (wave & 1) * 64;
  const int quad = lane >> 4, l16 = lane & 15;
#pragma unroll
  for (int i = 0; i < 4; ++i) {
    const int mb = m0 + wm + i * 16 + quad * 4;
#pragma unroll
    for (int r = 0; r < 4; ++r) {
      unsigned short* row = Sup2 + ((size_t)(mb + r) << 13);
#pragma unroll
      for (int j = 0; j < 4; ++j)
        row[n0 + wn + j * 16 + l16] = f2bf(acc[i][j][r]);
    }
  }
}

// ------- GEMM2: out = relu(adj@support / rowsum + bias + x) -------

__global__ __launch_bounds__(256) void k_gemm2(
    const unsigned short* __restrict__ AdjBf, // [8][1024][1024]
    const unsigned short* __restrict__ Sup2,  // [1024][8192]
    const float* __restrict__ x,
    const float* __restrict__ sumrow,         // [8][1024]
    const float* __restrict__ bias,           // [1024]
    float* __restrict__ out)
{
  __shared__ __align__(16) unsigned short lsm[4 * 8192];
  const int tid = threadIdx.x;
  const int n0 = blockIdx.x * 128, m0 = blockIdx.y * 128, b = blockIdx.z;

  f32x4 acc[4][4];
  zero_acc(acc);
  gemm_pipe(AdjBf + ((size_t)b << 20), 1024,
            Sup2 + ((size_t)b << 10), 8192,
            m0, n0, acc, lsm, tid);

  const float* xb = x   + ((size_t)b << 20);
  float*       ob = out + ((size_t)b << 20);
  const float* sr = sumrow + ((size_t)b << 10);
  const int lane = tid & 63, wave = tid >> 6;
  const int wm = (wave >> 1) * 64, wn = (wave & 1) * 64;
  const int quad = lane >> 4, l16 = lane & 15;

  float bv[4];
#pragma unroll
  for (int j = 0; j < 4; ++j) bv[j] = bias[n0 + wn + j * 16 + l16];

#pragma unroll
  for (int i = 0; i < 4; ++i) {
    const int mb = m0 + wm + i * 16 + quad * 4;
#pragma unroll
    for (int r = 0; r < 4; ++r) {
      const int m = mb + r;
      const float inv = 1.0f / sr[m];
#pragma unroll
      for (int j = 0; j < 4; ++j) {
        const int n = n0 + wn + j * 16 + l16;
        const size_t idx = (((size_t)m) << 10) + n;
        float v = acc[i][j][r] * inv + bv[j] + xb[idx];
        ob[idx] = fmaxf(v, 0.0f);
      }
    }
  }
}

// ---------------- launcher ----------------

extern "C" void kernel_launch(void* const* d_in, const int* in_sizes, int n_in,
                              void* d_out, int out_size, void* d_ws, size_t ws_size,
                              hipStream_t stream) {
  const float* x      = (const float*)d_in[0];
  const float* y      = (const float*)d_in[1];
  const float* adj    = (const float*)d_in[2];
  const float* sumrow = (const float*)d_in[3];
  const float* W      = (const float*)d_in[4];
  const float* bias   = (const float*)d_in[5];
  float* out = (float*)d_out;

  char* ws = (char*)d_ws;
  unsigned short* ybf   = (unsigned short*)(ws);                       // 16 MB
  unsigned short* adjbf = (unsigned short*)(ws + ((size_t)16 << 20));  // 16 MB
  unsigned short* wt    = (unsigned short*)(ws + ((size_t)32 << 20));  //  2 MB
  unsigned short* sup2  = (unsigned short*)(ws + ((size_t)34 << 20));  // 16 MB

  k_prep<<<dim3(16640), dim3(256), 0, stream>>>(
      (const float4*)y, (const float4*)adj, (ushort4*)ybf, (ushort4*)adjbf, W, wt);
  k_gemm1<<<dim3(64, 8), dim3(256), 0, stream>>>(wt, ybf, sup2);
  k_gemm2<<<dim3(8, 8, 8), dim3(256), 0, stream>>>(adjbf, sup2, x, sumrow, bias, out);
}